// Round 15
// baseline (210.149 us; speedup 1.0000x reference)
//
#include <hip/hip_runtime.h>
#include <math.h>

#define N_SETS 4096
#define SETS_PER_BLOCK 8
#define GRID_MAIN (N_SETS / SETS_PER_BLOCK)   // 512 blocks, all co-resident (2/CU)

typedef _Float16 f16;
typedef __attribute__((ext_vector_type(8))) _Float16 f16x8;
typedef __attribute__((ext_vector_type(4))) _Float16 f16x4;
typedef __attribute__((ext_vector_type(4))) float     f32x4;

// ---------------- ws layout ----------------
#define WS_PE    0         // fp32 [64][256]  65536
#define WS_QH    65536     // f16  [64][32]   4096
#define WS_WKV   69632     // f16  [64][256]  32768  (rows 0-31 Wk, 32-63 Wv)
#define WS_WMAPH 102400    // f16  [256][32]  16384
#define WS_PEH   118784    // f16  [64][256]  32768
#define WS_PTR   151552    // int  [4097]
#define WS_OUT   16777216  // probeS scratch, 202 MB (ws ~808 MB)

__device__ __forceinline__ void lds_barrier() {
    asm volatile("s_waitcnt lgkmcnt(0)" ::: "memory");
    __builtin_amdgcn_s_barrier();
    __builtin_amdgcn_sched_barrier(0);
}

// aux1: blocks [0,768) -> batch_ptr + out2 echo; blocks [768,832) -> pe table
__global__ void k_aux1(const int* __restrict__ batch, float* __restrict__ out2,
                       int* __restrict__ ptr, int N, float* __restrict__ pe) {
    int blk = blockIdx.x;
    if (blk < 768) {
        int i = blk * 256 + threadIdx.x;
        if (i >= N) return;
        int b = batch[i];
        out2[i] = (float)b;
        if (i == 0 || batch[i - 1] != b) ptr[b] = i;
        if (i == N - 1) ptr[N_SETS] = N;
    } else {
        int idx = (blk - 768) * 256 + threadIdx.x;   // 0..16383
        int p = idx >> 8, i = idx & 255;
        float e   = (float)(2 * (i / 2)) / 256.0f;
        float inv = powf(10000.0f, -e);
        float ang = (float)p * inv;
        pe[idx] = (i & 1) ? cosf(ang) : sinf(ang);
    }
}

// aux2: [0,96) weight f16 convert; [96,160) peh convert; [160,168) qh
__global__ void k_aux2(const float* __restrict__ Wk, const float* __restrict__ Wv,
                       const float* __restrict__ Wq, const float* __restrict__ Wmap,
                       const float* __restrict__ pe, f16* __restrict__ wkv,
                       f16* __restrict__ wmaph, f16* __restrict__ peh,
                       f16* __restrict__ qh) {
    int blk = blockIdx.x;
    if (blk < 96) {
        int idx = blk * 256 + threadIdx.x;           // 0..24575
        if (idx < 16384) {
            int j = idx >> 8, d = idx & 255;
            float v = (j < 32) ? Wk[j * 256 + d] : Wv[(j - 32) * 256 + d];
            wkv[idx] = (f16)v;
        } else {
            int i2 = idx - 16384;
            wmaph[i2] = (f16)Wmap[i2];
        }
    } else if (blk < 160) {
        int idx = (blk - 96) * 256 + threadIdx.x;    // 0..16383
        peh[idx] = (f16)pe[idx];
    } else {
        int idx = (blk - 160) * 256 + threadIdx.x;   // 0..2047
        int pos = idx >> 5, k = idx & 31;
        const float* pr = pe + pos * 256;
        const float* wr = Wq + k * 256;
        float s = 0.f;
        for (int d = 0; d < 256; d += 4) {
            float4 a = *(const float4*)(pr + d);
            float4 b = *(const float4*)(wr + d);
            s += a.x * b.x + a.y * b.y + a.z * b.z + a.w * b.w;
        }
        qh[idx] = (f16)s;
    }
}

// MODE 0: full (nt stores to out). MODE 1: loads-only (asm sink, no stores).
// MODE 2: stores-only (synth areg, stores to scratch).
template <int MODE>
__device__ __forceinline__ void body(
        const float* __restrict__ x,     const f16* __restrict__ wkv,
        const f16* __restrict__ wmaph,   const f16* __restrict__ qh,
        const f16* __restrict__ peh,     const float* __restrict__ bmap,
        const int* __restrict__ ptr,     float* __restrict__ out) {
    __shared__ char lds[47104];
    char* ysh = lds + 32768;
    char* zsh = lds + 40960;
    char* dsh = lds + 43008;

    const int t    = threadIdx.x;
    const int wv   = t >> 6;
    const int l15  = t & 15;
    const int lhi  = (t & 63) >> 4;
    const int arow = 16 * wv + l15;
    const int swz7 = (l15 & 7) << 4;

    int pv[SETS_PER_BLOCK + 1];
    #pragma unroll
    for (int i = 0; i <= SETS_PER_BLOCK; ++i)
        pv[i] = ptr[blockIdx.x * SETS_PER_BLOCK + i];

    #pragma unroll
    for (int i2 = 0; i2 < 8; ++i2) {
        int c = t + 256 * i2;
        int j = c >> 5, d0 = (c & 31) * 8;
        *(f16x8*)(lds + ((j * 512 + d0 * 2) ^ ((j & 7) << 4))) =
            *(const f16x8*)(wkv + j * 256 + d0);
    }
    f16x8 pef[8];
    #pragma unroll
    for (int ks = 0; ks < 8; ++ks)
        pef[ks] = *(const f16x8*)(peh + arow * 256 + ks * 32 + lhi * 8);
    const f16x8 qreg = *(const f16x8*)(qh + arow * 32 + lhi * 8);
    f16x8 bwreg[4];
    f32x4 biasc[4];
    #pragma unroll
    for (int i = 0; i < 4; ++i) {
        const int dcol = 64 * wv + 16 * i;
        bwreg[i] = *(const f16x8*)(wmaph + (dcol + l15) * 32 + lhi * 8);
        biasc[i] = *(const f32x4*)(bmap + dcol + lhi * 4);
    }

    float4 xf[16];
    if (MODE != 2) {
        const int s0 = pv[0], n0 = pv[1] - pv[0];
        if (arow < n0) {
            const float* xr = x + (size_t)(s0 + arow) * 256 + lhi * 8;
            #pragma unroll
            for (int ks = 0; ks < 8; ++ks) {
                xf[2 * ks]     = *(const float4*)(xr + ks * 32);
                xf[2 * ks + 1] = *(const float4*)(xr + ks * 32 + 4);
            }
        }
    }
    lds_barrier();

    for (int j = 0; j < SETS_PER_BLOCK; ++j) {
        const int s = pv[j], n = pv[j + 1] - s;
        const int n32 = (n + 31) & ~31;

        f16x8 areg[8];
        if (MODE == 2) {
            const f16 sc = (f16)(float)(j + 1);
            f16x8 scv;
            #pragma unroll
            for (int ii = 0; ii < 8; ++ii) scv[ii] = sc;
            #pragma unroll
            for (int ks = 0; ks < 8; ++ks) areg[ks] = pef[ks] * scv;
        } else if (arow < n) {
            #pragma unroll
            for (int ks = 0; ks < 8; ++ks) {
                float4 a = xf[2 * ks], a2 = xf[2 * ks + 1];
                f16x8 h;
                h[0]=(f16)a.x;  h[1]=(f16)a.y;  h[2]=(f16)a.z;  h[3]=(f16)a.w;
                h[4]=(f16)a2.x; h[5]=(f16)a2.y; h[6]=(f16)a2.z; h[7]=(f16)a2.w;
                areg[ks] = h + pef[ks];
            }
        } else {
            #pragma unroll
            for (int ks = 0; ks < 8; ++ks) {
                f16x8 h;
                #pragma unroll
                for (int ii = 0; ii < 8; ++ii) h[ii] = (f16)0.f;
                areg[ks] = h;
            }
        }
        if (MODE != 2 && j + 1 < SETS_PER_BLOCK) {
            const int s1 = pv[j + 1], n1 = pv[j + 2] - pv[j + 1];
            if (arow < n1) {
                const float* xr1 = x + (size_t)(s1 + arow) * 256 + lhi * 8;
                #pragma unroll
                for (int ks = 0; ks < 8; ++ks) {
                    xf[2 * ks]     = *(const float4*)(xr1 + ks * 32);
                    xf[2 * ks + 1] = *(const float4*)(xr1 + ks * 32 + 4);
                }
            }
        }

        // ---- GEMM1 ----
        if (16 * wv < n32) {
            f32x4 acc[4];
            #pragma unroll
            for (int nt = 0; nt < 4; ++nt) acc[nt] = (f32x4){0.f, 0.f, 0.f, 0.f};
            #pragma unroll
            for (int ks = 0; ks < 8; ++ks) {
                #pragma unroll
                for (int nt = 0; nt < 4; ++nt) {
                    f16x8 bf = *(const f16x8*)(lds +
                        (((16 * nt + l15) * 512 + ks * 64 + lhi * 16) ^ swz7));
                    acc[nt] = __builtin_amdgcn_mfma_f32_16x16x32_f16(areg[ks], bf, acc[nt], 0, 0, 0);
                }
            }
            const int row0 = 16 * wv + lhi * 4;
            #pragma unroll
            for (int nt = 0; nt < 4; ++nt) {
                const int col = 16 * nt + l15;
                f16x4 h4;
                #pragma unroll
                for (int q = 0; q < 4; ++q) h4[q] = (f16)acc[nt][q];
                *(f16x4*)(ysh + ((col * 128 + row0 * 2) ^ swz7)) = h4;
            }
        }
        lds_barrier();

        // ---- GEMM2 ----
        {
            const int it = wv >> 1, jt = wv & 1;
            f32x4 zacc = {0.f, 0.f, 0.f, 0.f};
            const int ca = 32 + 16 * it + l15, cb = 16 * jt + l15;
            const int nks = n32 >> 5;
            for (int ks = 0; ks < nks; ++ks) {
                const int r2 = ks * 64 + lhi * 16;
                f16x8 av = *(const f16x8*)(ysh + ((ca * 128 + r2) ^ swz7));
                f16x8 bk = *(const f16x8*)(ysh + ((cb * 128 + r2) ^ swz7));
                zacc = __builtin_amdgcn_mfma_f32_16x16x32_f16(av, bk, zacc, 0, 0, 0);
            }
            const int zc = 16 * jt + l15, zr0 = 16 * it + lhi * 4;
            f16x4 h4;
            #pragma unroll
            for (int q = 0; q < 4; ++q) h4[q] = (f16)zacc[q];
            *(f16x4*)(zsh + ((zc * 64 + zr0 * 2) ^ ((l15 & 3) << 4))) = h4;
        }
        lds_barrier();

        // ---- GEMM3 ----
        if (16 * wv < n) {
            const int k2 = lhi * 16;
            f16x8 bz0 = *(const f16x8*)(zsh + ((l15 * 64 + k2) ^ ((l15 & 3) << 4)));
            f16x8 bz1 = *(const f16x8*)(zsh + (((16 + l15) * 64 + k2) ^ ((l15 & 3) << 4)));
            f32x4 dd0 = {0.f, 0.f, 0.f, 0.f}, dd1 = {0.f, 0.f, 0.f, 0.f};
            dd0 = __builtin_amdgcn_mfma_f32_16x16x32_f16(qreg, bz0, dd0, 0, 0, 0);
            dd1 = __builtin_amdgcn_mfma_f32_16x16x32_f16(qreg, bz1, dd1, 0, 0, 0);
            #pragma unroll
            for (int q = 0; q < 4; ++q) {
                const int m = 16 * wv + lhi * 4 + q;
                *(f16*)(dsh + ((m * 64 + l15 * 2) ^ ((m & 7) << 4)))        = (f16)dd0[q];
                *(f16*)(dsh + ((m * 64 + (16 + l15) * 2) ^ ((m & 7) << 4))) = (f16)dd1[q];
            }
        }
        lds_barrier();

        // ---- GEMM4 (swapped, col-split) ----
        {
            const int k2 = lhi * 16;
            float* ob = out + (size_t)s * 256;
            #pragma unroll
            for (int mt = 0; mt < 4; ++mt) {
                if (16 * mt < n) {
                    f16x8 ad = *(const f16x8*)(dsh + (((16 * mt + l15) * 64 + k2) ^ swz7));
                    #pragma unroll
                    for (int i = 0; i < 4; ++i) {
                        f32x4 o = __builtin_amdgcn_mfma_f32_16x16x32_f16(bwreg[i], ad, biasc[i], 0, 0, 0);
                        float* dst = ob + (size_t)(16 * mt + l15) * 256 + 64 * wv + 16 * i + lhi * 4;
                        if (MODE == 1) {
                            asm volatile("" :: "v"(o[0]), "v"(o[1]), "v"(o[2]), "v"(o[3]));
                        } else if (MODE == 0) {
                            __builtin_nontemporal_store(o, (f32x4*)dst);
                        } else {
                            *(f32x4*)dst = o;
                        }
                    }
                }
            }
        }
    }
}

__global__ __launch_bounds__(256, 2) void k_main(
        const float* __restrict__ x,     const f16* __restrict__ wkv,
        const f16* __restrict__ wmaph,   const f16* __restrict__ qh,
        const f16* __restrict__ peh,     const float* __restrict__ bmap,
        const int* __restrict__ ptr,     float* __restrict__ out) {
    body<0>(x, wkv, wmaph, qh, peh, bmap, ptr, out);
}

__global__ __launch_bounds__(256, 2) void k_probeL(
        const float* __restrict__ x,     const f16* __restrict__ wkv,
        const f16* __restrict__ wmaph,   const f16* __restrict__ qh,
        const f16* __restrict__ peh,     const float* __restrict__ bmap,
        const int* __restrict__ ptr,     float* __restrict__ out) {
    body<1>(x, wkv, wmaph, qh, peh, bmap, ptr, out);
}

__global__ __launch_bounds__(256, 2) void k_probeS(
        const float* __restrict__ x,     const f16* __restrict__ wkv,
        const f16* __restrict__ wmaph,   const f16* __restrict__ qh,
        const f16* __restrict__ peh,     const float* __restrict__ bmap,
        const int* __restrict__ ptr,     float* __restrict__ out) {
    body<2>(x, wkv, wmaph, qh, peh, bmap, ptr, out);
}

extern "C" void kernel_launch(void* const* d_in, const int* in_sizes, int n_in,
                              void* d_out, int out_size, void* d_ws, size_t ws_size,
                              hipStream_t stream) {
    const float* x    = (const float*)d_in[0];
    const int*   batch= (const int*)  d_in[1];
    const float* Wk   = (const float*)d_in[2];
    const float* Wv   = (const float*)d_in[3];
    const float* Wq   = (const float*)d_in[4];
    const float* Wmap = (const float*)d_in[5];
    const float* bmap = (const float*)d_in[6];
    float* out = (float*)d_out;

    const int N = in_sizes[1];                 // 196608 rows
    float* pe    = (float*)((char*)d_ws + WS_PE);
    f16*   qh    = (f16*)  ((char*)d_ws + WS_QH);
    f16*   wkv   = (f16*)  ((char*)d_ws + WS_WKV);
    f16*   wmaph = (f16*)  ((char*)d_ws + WS_WMAPH);
    f16*   peh   = (f16*)  ((char*)d_ws + WS_PEH);
    int*   ptr   = (int*)  ((char*)d_ws + WS_PTR);
    float* wsout = (float*)((char*)d_ws + WS_OUT);
    float* out2  = out + (size_t)N * 256;      // output 1: batch echo as floats

    k_aux1<<<832, 256, 0, stream>>>(batch, out2, ptr, N, pe);
    k_aux2<<<168, 256, 0, stream>>>(Wk, Wv, Wq, Wmap, pe, wkv, wmaph, peh, qh);
    k_main<<<GRID_MAIN, 256, 0, stream>>>(x, wkv, wmaph, qh, peh, bmap, ptr, out);
    k_probeL<<<GRID_MAIN, 256, 0, stream>>>(x, wkv, wmaph, qh, peh, bmap, ptr, wsout);
    k_probeS<<<GRID_MAIN, 256, 0, stream>>>(x, wkv, wmaph, qh, peh, bmap, ptr, wsout);
}

// Round 16
// 116.171 us; speedup vs baseline: 1.8090x; 1.8090x over previous
//
#include <hip/hip_runtime.h>
#include <math.h>

#define N_SETS 4096
#define SETS_PER_BLOCK 8
#define GRID_MAIN (N_SETS / SETS_PER_BLOCK)   // 512 blocks, all co-resident (2/CU)

typedef _Float16 f16;
typedef __attribute__((ext_vector_type(8))) _Float16 f16x8;
typedef __attribute__((ext_vector_type(4))) _Float16 f16x4;
typedef __attribute__((ext_vector_type(4))) float     f32x4;

// ---------------- ws layout ----------------
#define WS_PE    0         // fp32 [64][256]  65536
#define WS_QH    65536     // f16  [64][32]   4096
#define WS_WKV   69632     // f16  [64][256]  32768  (rows 0-31 Wk, 32-63 Wv)
#define WS_WMAPH 102400    // f16  [256][32]  16384
#define WS_PEH   118784    // f16  [64][256]  32768
#define WS_PTR   151552    // int  [4097]

// Non-draining barrier: LDS visibility only; vmem stays in flight.
__device__ __forceinline__ void lds_barrier() {
    asm volatile("s_waitcnt lgkmcnt(0)" ::: "memory");
    __builtin_amdgcn_s_barrier();
    __builtin_amdgcn_sched_barrier(0);
}

// aux1: blocks [0,768) -> batch_ptr + out2 echo; blocks [768,832) -> pe table
__global__ void k_aux1(const int* __restrict__ batch, float* __restrict__ out2,
                       int* __restrict__ ptr, int N, float* __restrict__ pe) {
    int blk = blockIdx.x;
    if (blk < 768) {
        int i = blk * 256 + threadIdx.x;
        if (i >= N) return;
        int b = batch[i];
        out2[i] = (float)b;
        if (i == 0 || batch[i - 1] != b) ptr[b] = i;
        if (i == N - 1) ptr[N_SETS] = N;
    } else {
        int idx = (blk - 768) * 256 + threadIdx.x;   // 0..16383
        int p = idx >> 8, i = idx & 255;
        float e   = (float)(2 * (i / 2)) / 256.0f;
        float inv = powf(10000.0f, -e);
        float ang = (float)p * inv;
        pe[idx] = (i & 1) ? cosf(ang) : sinf(ang);
    }
}

// aux2: [0,96) weight f16 convert; [96,160) peh convert; [160,168) qh
__global__ void k_aux2(const float* __restrict__ Wk, const float* __restrict__ Wv,
                       const float* __restrict__ Wq, const float* __restrict__ Wmap,
                       const float* __restrict__ pe, f16* __restrict__ wkv,
                       f16* __restrict__ wmaph, f16* __restrict__ peh,
                       f16* __restrict__ qh) {
    int blk = blockIdx.x;
    if (blk < 96) {
        int idx = blk * 256 + threadIdx.x;           // 0..24575
        if (idx < 16384) {
            int j = idx >> 8, d = idx & 255;
            float v = (j < 32) ? Wk[j * 256 + d] : Wv[(j - 32) * 256 + d];
            wkv[idx] = (f16)v;
        } else {
            int i2 = idx - 16384;
            wmaph[i2] = (f16)Wmap[i2];
        }
    } else if (blk < 160) {
        int idx = (blk - 96) * 256 + threadIdx.x;    // 0..16383
        peh[idx] = (f16)pe[idx];
    } else {
        int idx = (blk - 160) * 256 + threadIdx.x;   // 0..2047
        int pos = idx >> 5, k = idx & 31;
        const float* pr = pe + pos * 256;
        const float* wr = Wq + k * 256;
        float s = 0.f;
        for (int d = 0; d < 256; d += 4) {
            float4 a = *(const float4*)(pr + d);
            float4 b = *(const float4*)(wr + d);
            s += a.x * b.x + a.y * b.y + a.z * b.z + a.w * b.w;
        }
        qh[idx] = (f16)s;
    }
}

// Stream-separated fused kernel.
// PHASE 1 (read-only vmem): for all 8 sets, G1 (Y=(X+PE)Wkv^T) + G2 (Z) with
//   zT parked in 8 LDS slots. Only x loads in flight -> per-set vmcnt waits
//   never touch stores.
// PHASE 2 (write-only vmem): for all 8 sets, G3+G4 from LDS z-slots, weights
//   in registers. Zero global loads -> stores are never drained mid-kernel.
// LDS map (61440 B -> 2 blocks/CU):
//   [0,     32768)  wsh f16 [64][256] swz ((j&7)<<4)  (Wk 0-31, Wv 32-63)
//   [32768, 40960)  ysh f16 [64c][64r] swz ((c&7)<<4)
//   [40960, 57344)  z8: 8 x (f16 [32c][32r] swz ((c&3)<<4))
//   [57344, 61440)  dsh f16 [64m][32v] swz ((m&7)<<4)
__global__ __launch_bounds__(256, 2) void k_main(
        const float* __restrict__ x,     const f16* __restrict__ wkv,
        const f16* __restrict__ wmaph,   const f16* __restrict__ qh,
        const f16* __restrict__ peh,     const float* __restrict__ bmap,
        const int* __restrict__ ptr,     float* __restrict__ out) {
    __shared__ char lds[61440];
    char* ysh = lds + 32768;
    char* dsh = lds + 57344;

    const int t    = threadIdx.x;
    const int wv   = t >> 6;
    const int l15  = t & 15;
    const int lhi  = (t & 63) >> 4;
    const int arow = 16 * wv + l15;
    const int swz7 = (l15 & 7) << 4;

    int pv[SETS_PER_BLOCK + 1];
    #pragma unroll
    for (int i = 0; i <= SETS_PER_BLOCK; ++i)
        pv[i] = ptr[blockIdx.x * SETS_PER_BLOCK + i];

    // ---- stage wsh (Wk|Wv) ----
    #pragma unroll
    for (int i2 = 0; i2 < 8; ++i2) {
        int c = t + 256 * i2;
        int j = c >> 5, d0 = (c & 31) * 8;
        *(f16x8*)(lds + ((j * 512 + d0 * 2) ^ ((j & 7) << 4))) =
            *(const f16x8*)(wkv + j * 256 + d0);
    }
    // ---- per-lane set-invariant registers ----
    f16x8 pef[8];
    #pragma unroll
    for (int ks = 0; ks < 8; ++ks)
        pef[ks] = *(const f16x8*)(peh + arow * 256 + ks * 32 + lhi * 8);
    const f16x8 qreg = *(const f16x8*)(qh + arow * 32 + lhi * 8);
    f16x8 bwreg[4];
    f32x4 biasc[4];
    #pragma unroll
    for (int i = 0; i < 4; ++i) {
        const int dcol = 64 * wv + 16 * i;
        bwreg[i] = *(const f16x8*)(wmaph + (dcol + l15) * 32 + lhi * 8);
        biasc[i] = *(const f32x4*)(bmap + dcol + lhi * 4);
    }

    // ---- prefetch set 0's x rows ----
    float4 xf[16];
    {
        const int s0 = pv[0], n0 = pv[1] - pv[0];
        if (arow < n0) {
            const float* xr = x + (size_t)(s0 + arow) * 256 + lhi * 8;
            #pragma unroll
            for (int ks = 0; ks < 8; ++ks) {
                xf[2 * ks]     = *(const float4*)(xr + ks * 32);
                xf[2 * ks + 1] = *(const float4*)(xr + ks * 32 + 4);
            }
        }
    }
    lds_barrier();

    // ================= PHASE 1: encoder (read stream only) =================
    for (int j = 0; j < SETS_PER_BLOCK; ++j) {
        const int s = pv[j], n = pv[j + 1] - s;
        const int n32 = (n + 31) & ~31;

        f16x8 areg[8];
        if (arow < n) {
            #pragma unroll
            for (int ks = 0; ks < 8; ++ks) {
                float4 a = xf[2 * ks], a2 = xf[2 * ks + 1];
                f16x8 h;
                h[0]=(f16)a.x;  h[1]=(f16)a.y;  h[2]=(f16)a.z;  h[3]=(f16)a.w;
                h[4]=(f16)a2.x; h[5]=(f16)a2.y; h[6]=(f16)a2.z; h[7]=(f16)a2.w;
                areg[ks] = h + pef[ks];
            }
        } else {
            #pragma unroll
            for (int ks = 0; ks < 8; ++ks) {
                f16x8 h;
                #pragma unroll
                for (int ii = 0; ii < 8; ++ii) h[ii] = (f16)0.f;
                areg[ks] = h;
            }
        }
        // prefetch next set's x (only loads in flight this phase)
        if (j + 1 < SETS_PER_BLOCK) {
            const int s1 = pv[j + 1], n1 = pv[j + 2] - pv[j + 1];
            if (arow < n1) {
                const float* xr1 = x + (size_t)(s1 + arow) * 256 + lhi * 8;
                #pragma unroll
                for (int ks = 0; ks < 8; ++ks) {
                    xf[2 * ks]     = *(const float4*)(xr1 + ks * 32);
                    xf[2 * ks + 1] = *(const float4*)(xr1 + ks * 32 + 4);
                }
            }
        }

        // ---- GEMM1: Y = (X+PE)*Wkv^T -> yshT ----
        if (16 * wv < n32) {
            f32x4 acc[4];
            #pragma unroll
            for (int nt = 0; nt < 4; ++nt) acc[nt] = (f32x4){0.f, 0.f, 0.f, 0.f};
            #pragma unroll
            for (int ks = 0; ks < 8; ++ks) {
                #pragma unroll
                for (int nt = 0; nt < 4; ++nt) {
                    f16x8 bf = *(const f16x8*)(lds +
                        (((16 * nt + l15) * 512 + ks * 64 + lhi * 16) ^ swz7));
                    acc[nt] = __builtin_amdgcn_mfma_f32_16x16x32_f16(areg[ks], bf, acc[nt], 0, 0, 0);
                }
            }
            const int row0 = 16 * wv + lhi * 4;
            #pragma unroll
            for (int nt = 0; nt < 4; ++nt) {
                const int col = 16 * nt + l15;
                f16x4 h4;
                #pragma unroll
                for (int q = 0; q < 4; ++q) h4[q] = (f16)acc[nt][q];
                *(f16x4*)(ysh + ((col * 128 + row0 * 2) ^ swz7)) = h4;
            }
        }
        lds_barrier();

        // ---- GEMM2: Z = YV^T * YK -> z slot j ----
        {
            const int it = wv >> 1, jt = wv & 1;
            f32x4 zacc = {0.f, 0.f, 0.f, 0.f};
            const int ca = 32 + 16 * it + l15, cb = 16 * jt + l15;
            const int nks = n32 >> 5;
            for (int ks = 0; ks < nks; ++ks) {
                const int r2 = ks * 64 + lhi * 16;
                f16x8 av = *(const f16x8*)(ysh + ((ca * 128 + r2) ^ swz7));
                f16x8 bk = *(const f16x8*)(ysh + ((cb * 128 + r2) ^ swz7));
                zacc = __builtin_amdgcn_mfma_f32_16x16x32_f16(av, bk, zacc, 0, 0, 0);
            }
            const int zc = 16 * jt + l15, zr0 = 16 * it + lhi * 4;
            f16x4 h4;
            #pragma unroll
            for (int q = 0; q < 4; ++q) h4[q] = (f16)zacc[q];
            *(f16x4*)(lds + 40960 + j * 2048 +
                      ((zc * 64 + zr0 * 2) ^ ((l15 & 3) << 4))) = h4;
        }
        lds_barrier();
    }

    // ================= PHASE 2: decoder (write stream only) ================
    for (int j = 0; j < SETS_PER_BLOCK; ++j) {
        const int s = pv[j], n = pv[j + 1] - s;
        char* zsh = lds + 40960 + j * 2048;

        // ---- GEMM3: dec = query * Z -> dsh ----
        if (16 * wv < n) {
            const int k2 = lhi * 16;
            f16x8 bz0 = *(const f16x8*)(zsh + ((l15 * 64 + k2) ^ ((l15 & 3) << 4)));
            f16x8 bz1 = *(const f16x8*)(zsh + (((16 + l15) * 64 + k2) ^ ((l15 & 3) << 4)));
            f32x4 dd0 = {0.f, 0.f, 0.f, 0.f}, dd1 = {0.f, 0.f, 0.f, 0.f};
            dd0 = __builtin_amdgcn_mfma_f32_16x16x32_f16(qreg, bz0, dd0, 0, 0, 0);
            dd1 = __builtin_amdgcn_mfma_f32_16x16x32_f16(qreg, bz1, dd1, 0, 0, 0);
            #pragma unroll
            for (int q = 0; q < 4; ++q) {
                const int m = 16 * wv + lhi * 4 + q;
                *(f16*)(dsh + ((m * 64 + l15 * 2) ^ ((m & 7) << 4)))        = (f16)dd0[q];
                *(f16*)(dsh + ((m * 64 + (16 + l15) * 2) ^ ((m & 7) << 4))) = (f16)dd1[q];
            }
        }
        lds_barrier();

        // ---- GEMM4 (swapped, col-split): stores never drained this phase ----
        {
            const int k2 = lhi * 16;
            float* ob = out + (size_t)s * 256;
            #pragma unroll
            for (int mt = 0; mt < 4; ++mt) {
                if (16 * mt < n) {
                    f16x8 ad = *(const f16x8*)(dsh + (((16 * mt + l15) * 64 + k2) ^ swz7));
                    #pragma unroll
                    for (int i = 0; i < 4; ++i) {
                        f32x4 o = __builtin_amdgcn_mfma_f32_16x16x32_f16(bwreg[i], ad, biasc[i], 0, 0, 0);
                        *(f32x4*)(ob + (size_t)(16 * mt + l15) * 256 + 64 * wv + 16 * i + lhi * 4) = o;
                    }
                }
            }
        }
        lds_barrier();   // protect dsh before next set's G3
    }
}

extern "C" void kernel_launch(void* const* d_in, const int* in_sizes, int n_in,
                              void* d_out, int out_size, void* d_ws, size_t ws_size,
                              hipStream_t stream) {
    const float* x    = (const float*)d_in[0];
    const int*   batch= (const int*)  d_in[1];
    const float* Wk   = (const float*)d_in[2];
    const float* Wv   = (const float*)d_in[3];
    const float* Wq   = (const float*)d_in[4];
    const float* Wmap = (const float*)d_in[5];
    const float* bmap = (const float*)d_in[6];
    float* out = (float*)d_out;

    const int N = in_sizes[1];                 // 196608 rows
    float* pe    = (float*)((char*)d_ws + WS_PE);
    f16*   qh    = (f16*)  ((char*)d_ws + WS_QH);
    f16*   wkv   = (f16*)  ((char*)d_ws + WS_WKV);
    f16*   wmaph = (f16*)  ((char*)d_ws + WS_WMAPH);
    f16*   peh   = (f16*)  ((char*)d_ws + WS_PEH);
    int*   ptr   = (int*)  ((char*)d_ws + WS_PTR);
    float* out2  = out + (size_t)N * 256;      // output 1: batch echo as floats

    k_aux1<<<832, 256, 0, stream>>>(batch, out2, ptr, N, pe);
    k_aux2<<<168, 256, 0, stream>>>(Wk, Wv, Wq, Wmap, pe, wkv, wmaph, peh, qh);
    k_main<<<GRID_MAIN, 256, 0, stream>>>(x, wkv, wmaph, qh, peh, bmap, ptr, out);
}